// Round 1
// baseline (226.594 us; speedup 1.0000x reference)
//
#include <hip/hip_runtime.h>
#include <hip/hip_bf16.h>
#include <stdint.h>

#define BATCH 4
#define L_SEQ 2048
#define DIM   1024

typedef __bf16 bf16;
typedef __bf16 bf16x4 __attribute__((ext_vector_type(4)));
typedef __bf16 bf16x8 __attribute__((ext_vector_type(8)));
typedef float  f32x4  __attribute__((ext_vector_type(4)));

// ---------------- fp32 -> bf16 convert (vectorized x4) ----------------
__global__ __launch_bounds__(256)
void cvt_f32_bf16(const float* __restrict__ in, bf16* __restrict__ out, int n4)
{
    int i = blockIdx.x * 256 + threadIdx.x;
    if (i >= n4) return;
    float4 v = ((const float4*)in)[i];
    bf16x4 o = { (bf16)v.x, (bf16)v.y, (bf16)v.z, (bf16)v.w };
    ((bf16x4*)out)[i] = o;
}

// ---------------- unified 128x128-tile bf16 MFMA GEMM ----------------
// All operands are "B^T layout": A[m][k], B[n][k], both K-contiguous.
// C[m][n] = sum_k A[m][k]*B[n][k]  (fp32 accum), epilogue per MODE.
#define MODE_QK 0   // out bf16 row-major [m][n] + bias[n]        (Q, K proj)
#define MODE_VT 1   // out bf16 transposed Vt[b][n][l] + bias[n]  (V proj)
#define MODE_SC 2   // out fp32 scores[b][q][k] * 1/32, skip masked tiles
#define MODE_PV 3   // out fp32 out[b][q][e], causal K-loop truncation

template<int MODE>
__global__ __launch_bounds__(256)
void gemm128(const bf16* __restrict__ Abase, const bf16* __restrict__ Bbase,
             const float* __restrict__ bias, void* __restrict__ outp)
{
    __shared__ __align__(16) bf16 As[128 * 32];
    __shared__ __align__(16) bf16 Bs[128 * 32];

    const int m0 = blockIdx.x * 128;
    const int n0 = blockIdx.y * 128;
    const int z  = blockIdx.z;

    const bf16* A; const bf16* Bm;
    int lda, ldb, kIters;
    if constexpr (MODE == MODE_QK || MODE == MODE_VT) {
        A = Abase; Bm = Bbase; lda = DIM; ldb = DIM; kIters = DIM / 32;
    } else if constexpr (MODE == MODE_SC) {
        if (n0 > m0) return;                    // fully-masked tile: softmax writes the zeros
        A  = Abase + (size_t)z * L_SEQ * DIM;
        Bm = Bbase + (size_t)z * L_SEQ * DIM;
        lda = DIM; ldb = DIM; kIters = DIM / 32;
    } else { // MODE_PV
        A  = Abase + (size_t)z * L_SEQ * L_SEQ;
        Bm = Bbase + (size_t)z * DIM * L_SEQ;
        lda = L_SEQ; ldb = L_SEQ; kIters = (m0 + 128) >> 5;   // wts==0 beyond the diagonal block
    }

    const int tid  = threadIdx.x;
    const int w    = tid >> 6;
    const int lane = tid & 63;
    const int wr   = w >> 1, wc = w & 1;

    f32x4 acc[4][4];
#pragma unroll
    for (int i = 0; i < 4; ++i)
#pragma unroll
        for (int j = 0; j < 4; ++j) acc[i][j] = (f32x4){0.f, 0.f, 0.f, 0.f};

    // staging: tile is [128 rows][32 cols] bf16, linear. Each wave-issue covers
    // 1 KiB (64 lanes x 16 B); per-lane global src must match lds_base + lane*16.
    const int e0 = w * 512 + lane * 8;          // chunk0 element offset
    const int r0 = e0 >> 5, c0 = e0 & 31;
    const int r1 = r0 + 64;                      // chunk1 = +2048 elems

    char* AsB = (char*)As;
    char* BsB = (char*)Bs;
    const int lds0 = w * 1024;                   // wave-uniform byte base, chunk0
    const int lds1 = 4096 + w * 1024;            // chunk1

    const int frow = lane & 15;                  // fragment row/col
    const int fk   = (lane >> 4) << 3;           // fragment k offset (x8 bf16)

    for (int kt = 0; kt < kIters; ++kt) {
        const int k0 = kt << 5;
        const bf16* a0 = A  + (size_t)(m0 + r0) * lda + (k0 + c0);
        const bf16* a1 = A  + (size_t)(m0 + r1) * lda + (k0 + c0);
        const bf16* b0 = Bm + (size_t)(n0 + r0) * ldb + (k0 + c0);
        const bf16* b1 = Bm + (size_t)(n0 + r1) * ldb + (k0 + c0);
        __builtin_amdgcn_global_load_lds((const __attribute__((address_space(1))) void*)a0,
                                         (__attribute__((address_space(3))) void*)(AsB + lds0), 16, 0, 0);
        __builtin_amdgcn_global_load_lds((const __attribute__((address_space(1))) void*)a1,
                                         (__attribute__((address_space(3))) void*)(AsB + lds1), 16, 0, 0);
        __builtin_amdgcn_global_load_lds((const __attribute__((address_space(1))) void*)b0,
                                         (__attribute__((address_space(3))) void*)(BsB + lds0), 16, 0, 0);
        __builtin_amdgcn_global_load_lds((const __attribute__((address_space(1))) void*)b1,
                                         (__attribute__((address_space(3))) void*)(BsB + lds1), 16, 0, 0);
        __syncthreads();   // compiler inserts vmcnt(0) drain before barrier

        bf16x8 af[4], bfr[4];
#pragma unroll
        for (int i = 0; i < 4; ++i) {
            int r = wr * 64 + i * 16 + frow;
            af[i] = *(const bf16x8*)(As + r * 32 + fk);
        }
#pragma unroll
        for (int j = 0; j < 4; ++j) {
            int c = wc * 64 + j * 16 + frow;
            bfr[j] = *(const bf16x8*)(Bs + c * 32 + fk);
        }
#pragma unroll
        for (int i = 0; i < 4; ++i)
#pragma unroll
            for (int j = 0; j < 4; ++j)
                acc[i][j] = __builtin_amdgcn_mfma_f32_16x16x32_bf16(af[i], bfr[j], acc[i][j], 0, 0, 0);
        __syncthreads();
    }

    // ---- epilogue: C/D layout col = lane&15, row = (lane>>4)*4 + r ----
    const int lr = (lane >> 4) << 2;
    const int lc = lane & 15;

    if constexpr (MODE == MODE_QK) {
        bf16* out = (bf16*)outp;
#pragma unroll
        for (int i = 0; i < 4; ++i) {
            int row0 = m0 + wr * 64 + i * 16 + lr;
#pragma unroll
            for (int j = 0; j < 4; ++j) {
                int col = n0 + wc * 64 + j * 16 + lc;
                float bb = bias[col];
#pragma unroll
                for (int r = 0; r < 4; ++r)
                    out[(size_t)(row0 + r) * DIM + col] = (bf16)(acc[i][j][r] + bb);
            }
        }
    } else if constexpr (MODE == MODE_VT) {
        bf16* Vt = (bf16*)outp;
#pragma unroll
        for (int i = 0; i < 4; ++i) {
            int row0 = m0 + wr * 64 + i * 16 + lr;
            int b = row0 >> 11, l = row0 & 2047;
#pragma unroll
            for (int j = 0; j < 4; ++j) {
                int col = n0 + wc * 64 + j * 16 + lc;
                float bb = bias[col];
                bf16x4 v = { (bf16)(acc[i][j][0] + bb), (bf16)(acc[i][j][1] + bb),
                             (bf16)(acc[i][j][2] + bb), (bf16)(acc[i][j][3] + bb) };
                *(bf16x4*)(Vt + ((size_t)b * DIM + col) * L_SEQ + l) = v;  // 4 consecutive l
            }
        }
    } else if constexpr (MODE == MODE_SC) {
        float* sc = (float*)outp + (size_t)z * L_SEQ * L_SEQ;
#pragma unroll
        for (int i = 0; i < 4; ++i) {
            int row0 = m0 + wr * 64 + i * 16 + lr;
#pragma unroll
            for (int j = 0; j < 4; ++j) {
                int col = n0 + wc * 64 + j * 16 + lc;
#pragma unroll
                for (int r = 0; r < 4; ++r)
                    sc[(size_t)(row0 + r) * L_SEQ + col] = acc[i][j][r] * 0.03125f;
            }
        }
    } else { // MODE_PV
        float* o = (float*)outp + (size_t)z * L_SEQ * DIM;
#pragma unroll
        for (int i = 0; i < 4; ++i) {
            int row0 = m0 + wr * 64 + i * 16 + lr;
#pragma unroll
            for (int j = 0; j < 4; ++j) {
                int col = n0 + wc * 64 + j * 16 + lc;
#pragma unroll
                for (int r = 0; r < 4; ++r)
                    o[(size_t)(row0 + r) * DIM + col] = acc[i][j][r];
            }
        }
    }
}

// ---------------- causal row softmax: wts fp32 (in-place) + bf16 copy ----------------
__global__ __launch_bounds__(256)
void softmax_rows(float* __restrict__ wts, bf16* __restrict__ Pb)
{
    const int row = blockIdx.x;                 // 0..8191
    const int b = row >> 11, q = row & 2047;
    float* s = wts + ((size_t)b * L_SEQ + q) * L_SEQ;
    bf16*  p = Pb  + (size_t)row * L_SEQ;
    const int t = threadIdx.x;
    const int lane = t & 63, w = t >> 6;

    float v[8];
    float mx = -3.0e38f;
#pragma unroll
    for (int c = 0; c < 8; ++c) {
        int k = t + c * 256;
        float x = s[k];                          // garbage beyond diagonal is masked below
        v[c] = (k <= q) ? x : -3.0e38f;
        mx = fmaxf(mx, v[c]);
    }
#pragma unroll
    for (int off = 32; off; off >>= 1) mx = fmaxf(mx, __shfl_xor(mx, off));
    __shared__ float redm[4];
    if (lane == 0) redm[w] = mx;
    __syncthreads();
    mx = fmaxf(fmaxf(redm[0], redm[1]), fmaxf(redm[2], redm[3]));

    float sm = 0.f;
#pragma unroll
    for (int c = 0; c < 8; ++c) {
        float e = __expf(v[c] - mx);             // masked -> exp(-3e38) == 0 exactly
        v[c] = e;
        sm += e;
    }
#pragma unroll
    for (int off = 32; off; off >>= 1) sm += __shfl_xor(sm, off);
    __shared__ float reds[4];
    if (lane == 0) reds[w] = sm;
    __syncthreads();
    sm = reds[0] + reds[1] + reds[2] + reds[3];
    const float inv = 1.f / sm;

#pragma unroll
    for (int c = 0; c < 8; ++c) {
        int k = t + c * 256;
        float o = v[c] * inv;                    // masked entries: exactly 0.0 (matches ref underflow)
        s[k] = o;
        p[k] = (bf16)o;
    }
}

extern "C" void kernel_launch(void* const* d_in, const int* in_sizes, int n_in,
                              void* d_out, int out_size, void* d_ws, size_t ws_size,
                              hipStream_t stream)
{
    const float* x  = (const float*)d_in[0];
    const float* Wq = (const float*)d_in[1];
    const float* bq = (const float*)d_in[2];
    const float* Wk = (const float*)d_in[3];
    const float* bk = (const float*)d_in[4];
    const float* Wv = (const float*)d_in[5];
    const float* bv = (const float*)d_in[6];

    float* out = (float*)d_out;                               // [4][2048][1024]
    float* wts = out + (size_t)BATCH * L_SEQ * DIM;           // [4][2048][2048]

    // workspace layout (bytes): bf16 copies of everything MFMA touches
    char* ws = (char*)d_ws;
    bf16* Xb  = (bf16*)(ws + 0);          // 16 MiB   [8192][1024]
    bf16* Wqb = (bf16*)(ws + 16777216);   // 2 MiB
    bf16* Wkb = (bf16*)(ws + 18874368);   // 2 MiB
    bf16* Wvb = (bf16*)(ws + 20971520);   // 2 MiB
    bf16* Qb  = (bf16*)(ws + 23068672);   // 16 MiB   [b][l][e]
    bf16* Kb  = (bf16*)(ws + 39845888);   // 16 MiB   [b][l][e]
    bf16* Vt  = (bf16*)(ws + 56623104);   // 16 MiB   [b][e][l]  (transposed)
    bf16* Pb  = (bf16*)(ws + 73400320);   // 32 MiB   [b][q][k]  (bf16 wts)

    cvt_f32_bf16<<<dim3(8192), dim3(256), 0, stream>>>(x,  Xb,  8388608 / 4);
    cvt_f32_bf16<<<dim3(1024), dim3(256), 0, stream>>>(Wq, Wqb, 1048576 / 4);
    cvt_f32_bf16<<<dim3(1024), dim3(256), 0, stream>>>(Wk, Wkb, 1048576 / 4);
    cvt_f32_bf16<<<dim3(1024), dim3(256), 0, stream>>>(Wv, Wvb, 1048576 / 4);

    gemm128<MODE_QK><<<dim3(64, 8, 1),  dim3(256), 0, stream>>>(Xb, Wqb, bq, Qb);
    gemm128<MODE_QK><<<dim3(64, 8, 1),  dim3(256), 0, stream>>>(Xb, Wkb, bk, Kb);
    gemm128<MODE_VT><<<dim3(64, 8, 1),  dim3(256), 0, stream>>>(Xb, Wvb, bv, Vt);
    gemm128<MODE_SC><<<dim3(16, 16, 4), dim3(256), 0, stream>>>(Qb, Kb, nullptr, wts);
    softmax_rows<<<dim3(8192), dim3(256), 0, stream>>>(wts, Pb);
    gemm128<MODE_PV><<<dim3(16, 8, 4),  dim3(256), 0, stream>>>(Pb, Vt, nullptr, out);
}

// Round 2
// 220.912 us; speedup vs baseline: 1.0257x; 1.0257x over previous
//
#include <hip/hip_runtime.h>
#include <hip/hip_bf16.h>
#include <stdint.h>

#define BATCH 4
#define L_SEQ 2048
#define DIM   1024

typedef __bf16 bf16;
typedef __bf16 bf16x4 __attribute__((ext_vector_type(4)));
typedef __bf16 bf16x8 __attribute__((ext_vector_type(8)));
typedef float  f32x4  __attribute__((ext_vector_type(4)));

// ---------------- fp32 -> bf16 convert (vectorized x4) ----------------
__global__ __launch_bounds__(256)
void cvt_f32_bf16(const float* __restrict__ in, bf16* __restrict__ out, int n4)
{
    int i = blockIdx.x * 256 + threadIdx.x;
    if (i >= n4) return;
    float4 v = ((const float4*)in)[i];
    bf16x4 o = { (bf16)v.x, (bf16)v.y, (bf16)v.z, (bf16)v.w };
    ((bf16x4*)out)[i] = o;
}

// ---------------- unified 128x128-tile bf16 MFMA GEMM (double-buffered) ----------------
// A[m][k], B[n][k], K-contiguous. C[m][n] = sum_k A[m][k]*B[n][k], fp32 accum.
#define MODE_QKV 0  // fused QKV: B = [Wq;Wk;Wv] (3072 rows). col<1024->Q bf16, <2048->K bf16, else->Vt transposed. +bias
#define MODE_SC  2  // scores[b][q][k] fp32 * 1/32, skip masked tiles
#define MODE_PV  3  // out[b][q][e] fp32, causal K truncation

template<int MODE>
__global__ __launch_bounds__(256)
void gemm128(const bf16* __restrict__ Abase, const bf16* __restrict__ Bbase,
             const float* __restrict__ bqp, const float* __restrict__ bkp,
             const float* __restrict__ bvp,
             void* __restrict__ o0, void* __restrict__ o1, void* __restrict__ o2)
{
    __shared__ __align__(16) bf16 As[2 * 4096];   // 2 x [128][32]
    __shared__ __align__(16) bf16 Bs[2 * 4096];

    // heavy causal blocks (large m0) first for tail balance
    const int bx = (MODE == MODE_SC || MODE == MODE_PV) ? (gridDim.x - 1 - blockIdx.x)
                                                        : blockIdx.x;
    const int m0 = bx * 128;
    const int n0 = blockIdx.y * 128;
    const int z  = blockIdx.z;

    const bf16* A; const bf16* Bm;
    int lda, ldb, kIters;
    if constexpr (MODE == MODE_QKV) {
        A = Abase; Bm = Bbase; lda = DIM; ldb = DIM; kIters = DIM / 32;
    } else if constexpr (MODE == MODE_SC) {
        if (n0 > m0) return;                    // fully-masked tile: softmax writes the zeros
        A  = Abase + (size_t)z * L_SEQ * DIM;
        Bm = Bbase + (size_t)z * L_SEQ * DIM;
        lda = DIM; ldb = DIM; kIters = DIM / 32;
    } else { // MODE_PV
        A  = Abase + (size_t)z * L_SEQ * L_SEQ;
        Bm = Bbase + (size_t)z * DIM * L_SEQ;
        lda = L_SEQ; ldb = L_SEQ; kIters = (m0 + 128) >> 5;   // wts==0 beyond diagonal block
    }

    const int tid  = threadIdx.x;
    const int w    = tid >> 6;
    const int lane = tid & 63;
    const int wr   = w >> 1, wc = w & 1;

    f32x4 acc[4][4];
#pragma unroll
    for (int i = 0; i < 4; ++i)
#pragma unroll
        for (int j = 0; j < 4; ++j) acc[i][j] = (f32x4){0.f, 0.f, 0.f, 0.f};

    // staging geometry: tile [128 rows][32 cols] bf16 linear; 1 KiB per wave-issue
    const int e0 = w * 512 + lane * 8;
    const int r0 = e0 >> 5, c0 = e0 & 31;
    const int r1 = r0 + 64;
    const int ldsw = w * 1024;                   // wave-uniform byte base within 4 KiB half

    auto stage = [&](int buf, int kt) {
        const int k0 = kt << 5;
        const bf16* a0 = A  + (size_t)(m0 + r0) * lda + (k0 + c0);
        const bf16* a1 = A  + (size_t)(m0 + r1) * lda + (k0 + c0);
        const bf16* b0 = Bm + (size_t)(n0 + r0) * ldb + (k0 + c0);
        const bf16* b1 = Bm + (size_t)(n0 + r1) * ldb + (k0 + c0);
        char* ad0 = (char*)As + buf * 8192 + ldsw;
        char* ad1 = (char*)As + buf * 8192 + 4096 + ldsw;
        char* bd0 = (char*)Bs + buf * 8192 + ldsw;
        char* bd1 = (char*)Bs + buf * 8192 + 4096 + ldsw;
        __builtin_amdgcn_global_load_lds((const __attribute__((address_space(1))) void*)a0,
                                         (__attribute__((address_space(3))) void*)ad0, 16, 0, 0);
        __builtin_amdgcn_global_load_lds((const __attribute__((address_space(1))) void*)a1,
                                         (__attribute__((address_space(3))) void*)ad1, 16, 0, 0);
        __builtin_amdgcn_global_load_lds((const __attribute__((address_space(1))) void*)b0,
                                         (__attribute__((address_space(3))) void*)bd0, 16, 0, 0);
        __builtin_amdgcn_global_load_lds((const __attribute__((address_space(1))) void*)b1,
                                         (__attribute__((address_space(3))) void*)bd1, 16, 0, 0);
    };

    const int frow = lane & 15;
    const int fk   = (lane >> 4) << 3;

    stage(0, 0);                                 // prologue: fill buf0 (4 loads/wave in flight)
    int cur = 0;
    for (int kt = 0; kt < kIters; ++kt) {
        if (kt + 1 < kIters) {
            stage(cur ^ 1, kt + 1);              // prefetch next tile (4 more loads/wave)
            asm volatile("s_waitcnt vmcnt(4)" ::: "memory");   // cur tile resident; prefetch stays in flight
        } else {
            asm volatile("s_waitcnt vmcnt(0)" ::: "memory");
        }
        __builtin_amdgcn_s_barrier();
        __builtin_amdgcn_sched_barrier(0);

        const bf16* Ab = As + cur * 4096;
        const bf16* Bb = Bs + cur * 4096;
        bf16x8 af[4], bfr[4];
#pragma unroll
        for (int i = 0; i < 4; ++i) {
            int r = wr * 64 + i * 16 + frow;
            af[i] = *(const bf16x8*)(Ab + r * 32 + fk);
        }
#pragma unroll
        for (int j = 0; j < 4; ++j) {
            int c = wc * 64 + j * 16 + frow;
            bfr[j] = *(const bf16x8*)(Bb + c * 32 + fk);
        }
#pragma unroll
        for (int i = 0; i < 4; ++i)
#pragma unroll
            for (int j = 0; j < 4; ++j)
                acc[i][j] = __builtin_amdgcn_mfma_f32_16x16x32_bf16(af[i], bfr[j], acc[i][j], 0, 0, 0);

        asm volatile("s_waitcnt lgkmcnt(0)" ::: "memory");  // frag reads of cur done
        __builtin_amdgcn_s_barrier();                        // does NOT drain vmcnt -> prefetch lives on
        __builtin_amdgcn_sched_barrier(0);
        cur ^= 1;
    }

    // ---- epilogue: C/D layout col = lane&15, row = (lane>>4)*4 + r ----
    const int lr = (lane >> 4) << 2;
    const int lc = lane & 15;

    if constexpr (MODE == MODE_QKV) {
        const int sel = n0 >> 10;                // 0:Q 1:K 2:V   (128 | 1024 so block-uniform)
        const int nl0 = n0 & 1023;
        const float* bias = sel == 0 ? bqp : (sel == 1 ? bkp : bvp);
        if (sel < 2) {
            bf16* out = sel == 0 ? (bf16*)o0 : (bf16*)o1;
#pragma unroll
            for (int i = 0; i < 4; ++i) {
                int row0 = m0 + wr * 64 + i * 16 + lr;
#pragma unroll
                for (int j = 0; j < 4; ++j) {
                    int col = nl0 + wc * 64 + j * 16 + lc;
                    float bb = bias[col];
#pragma unroll
                    for (int r = 0; r < 4; ++r)
                        out[(size_t)(row0 + r) * DIM + col] = (bf16)(acc[i][j][r] + bb);
                }
            }
        } else {
            bf16* Vt = (bf16*)o2;
#pragma unroll
            for (int i = 0; i < 4; ++i) {
                int row0 = m0 + wr * 64 + i * 16 + lr;
                int b = row0 >> 11, l = row0 & 2047;
#pragma unroll
                for (int j = 0; j < 4; ++j) {
                    int col = nl0 + wc * 64 + j * 16 + lc;
                    float bb = bias[col];
                    bf16x4 v = { (bf16)(acc[i][j][0] + bb), (bf16)(acc[i][j][1] + bb),
                                 (bf16)(acc[i][j][2] + bb), (bf16)(acc[i][j][3] + bb) };
                    *(bf16x4*)(Vt + ((size_t)b * DIM + col) * L_SEQ + l) = v;
                }
            }
        }
    } else if constexpr (MODE == MODE_SC) {
        float* sc = (float*)o0 + (size_t)z * L_SEQ * L_SEQ;
#pragma unroll
        for (int i = 0; i < 4; ++i) {
            int row0 = m0 + wr * 64 + i * 16 + lr;
#pragma unroll
            for (int j = 0; j < 4; ++j) {
                int col = n0 + wc * 64 + j * 16 + lc;
#pragma unroll
                for (int r = 0; r < 4; ++r)
                    sc[(size_t)(row0 + r) * L_SEQ + col] = acc[i][j][r] * 0.03125f;
            }
        }
    } else { // MODE_PV
        float* o = (float*)o0 + (size_t)z * L_SEQ * DIM;
#pragma unroll
        for (int i = 0; i < 4; ++i) {
            int row0 = m0 + wr * 64 + i * 16 + lr;
#pragma unroll
            for (int j = 0; j < 4; ++j) {
                int col = n0 + wc * 64 + j * 16 + lc;
#pragma unroll
                for (int r = 0; r < 4; ++r)
                    o[(size_t)(row0 + r) * DIM + col] = acc[i][j][r];
            }
        }
    }
}

// ---------------- causal row softmax: wts fp32 (in-place) + bf16 copy ----------------
// thread t owns k = t*8 .. t*8+7 (contiguous) -> float4/bf16x8 vector IO;
// loads predicated on k<=q so the masked suffix is never fetched.
__global__ __launch_bounds__(256)
void softmax_rows(float* __restrict__ wts, bf16* __restrict__ Pb)
{
    const int row = blockIdx.x;                 // 0..8191
    const int q = row & 2047;
    float* s = wts + (size_t)row * L_SEQ;
    bf16*  p = Pb  + (size_t)row * L_SEQ;
    const int t = threadIdx.x;
    const int lane = t & 63, w = t >> 6;
    const int k0 = t * 8;

    float v[8];
    if (k0 + 7 <= q) {
        float4 a = *(const float4*)(s + k0);
        float4 b = *(const float4*)(s + k0 + 4);
        v[0]=a.x; v[1]=a.y; v[2]=a.z; v[3]=a.w;
        v[4]=b.x; v[5]=b.y; v[6]=b.z; v[7]=b.w;
    } else {
#pragma unroll
        for (int c = 0; c < 8; ++c) {
            int k = k0 + c;
            v[c] = (k <= q) ? s[k] : -3.0e38f;
        }
    }

    float mx = v[0];
#pragma unroll
    for (int c = 1; c < 8; ++c) mx = fmaxf(mx, v[c]);
#pragma unroll
    for (int off = 32; off; off >>= 1) mx = fmaxf(mx, __shfl_xor(mx, off));
    __shared__ float redm[4];
    if (lane == 0) redm[w] = mx;
    __syncthreads();
    mx = fmaxf(fmaxf(redm[0], redm[1]), fmaxf(redm[2], redm[3]));

    float sm = 0.f;
#pragma unroll
    for (int c = 0; c < 8; ++c) {
        float e = __expf(v[c] - mx);             // masked -> exp(-3e38) == 0 exactly
        v[c] = e;
        sm += e;
    }
#pragma unroll
    for (int off = 32; off; off >>= 1) sm += __shfl_xor(sm, off);
    __shared__ float reds[4];
    if (lane == 0) reds[w] = sm;
    __syncthreads();
    sm = reds[0] + reds[1] + reds[2] + reds[3];
    const float inv = 1.f / sm;

    float o[8];
#pragma unroll
    for (int c = 0; c < 8; ++c) o[c] = v[c] * inv;   // masked entries: exactly 0.0
    float4 s0 = { o[0], o[1], o[2], o[3] };
    float4 s1 = { o[4], o[5], o[6], o[7] };
    *(float4*)(s + k0)     = s0;
    *(float4*)(s + k0 + 4) = s1;
    bf16x8 pb = { (bf16)o[0], (bf16)o[1], (bf16)o[2], (bf16)o[3],
                  (bf16)o[4], (bf16)o[5], (bf16)o[6], (bf16)o[7] };
    *(bf16x8*)(p + k0) = pb;
}

extern "C" void kernel_launch(void* const* d_in, const int* in_sizes, int n_in,
                              void* d_out, int out_size, void* d_ws, size_t ws_size,
                              hipStream_t stream)
{
    const float* x  = (const float*)d_in[0];
    const float* Wq = (const float*)d_in[1];
    const float* bq = (const float*)d_in[2];
    const float* Wk = (const float*)d_in[3];
    const float* bk = (const float*)d_in[4];
    const float* Wv = (const float*)d_in[5];
    const float* bv = (const float*)d_in[6];

    float* out = (float*)d_out;                               // [4][2048][1024]
    float* wts = out + (size_t)BATCH * L_SEQ * DIM;           // [4][2048][2048]

    // workspace layout (MiB offsets)
    char* ws = (char*)d_ws;
    bf16* Xb   = (bf16*)(ws + 0);                  // 16 MiB  [8192][1024]
    bf16* Wcat = (bf16*)(ws + (16u  << 20));       //  6 MiB  [3072][1024]  (Wq;Wk;Wv)
    bf16* Qb   = (bf16*)(ws + (22u  << 20));       // 16 MiB  [b][l][e]
    bf16* Kb   = (bf16*)(ws + (38u  << 20));       // 16 MiB  [b][l][e]
    bf16* Vt   = (bf16*)(ws + (54u  << 20));       // 16 MiB  [b][e][l]
    bf16* Pb   = (bf16*)(ws + (70u  << 20));       // 32 MiB  [b][q][k]

    cvt_f32_bf16<<<dim3(8192), dim3(256), 0, stream>>>(x,  Xb, 8388608 / 4);
    cvt_f32_bf16<<<dim3(1024), dim3(256), 0, stream>>>(Wq, Wcat,               1048576 / 4);
    cvt_f32_bf16<<<dim3(1024), dim3(256), 0, stream>>>(Wk, Wcat + 1048576,     1048576 / 4);
    cvt_f32_bf16<<<dim3(1024), dim3(256), 0, stream>>>(Wv, Wcat + 2097152,     1048576 / 4);

    gemm128<MODE_QKV><<<dim3(64, 24, 1), dim3(256), 0, stream>>>(Xb, Wcat, bq, bk, bv, Qb, Kb, Vt);
    gemm128<MODE_SC> <<<dim3(16, 16, 4), dim3(256), 0, stream>>>(Qb, Kb, nullptr, nullptr, nullptr, wts, nullptr, nullptr);
    softmax_rows<<<dim3(8192), dim3(256), 0, stream>>>(wts, Pb);
    gemm128<MODE_PV> <<<dim3(16, 8, 4),  dim3(256), 0, stream>>>(Pb, Vt, nullptr, nullptr, nullptr, out, nullptr, nullptr);
}

// Round 3
// 202.016 us; speedup vs baseline: 1.1217x; 1.0935x over previous
//
#include <hip/hip_runtime.h>
#include <hip/hip_bf16.h>
#include <stdint.h>

#define BATCH 4
#define L_SEQ 2048
#define DIM   1024

typedef __bf16 bf16;
typedef __bf16 bf16x4 __attribute__((ext_vector_type(4)));
typedef __bf16 bf16x8 __attribute__((ext_vector_type(8)));
typedef float  f32x4  __attribute__((ext_vector_type(4)));

#define GLDS(src, dst) __builtin_amdgcn_global_load_lds(\
    (const __attribute__((address_space(1))) void*)(src), \
    (__attribute__((address_space(3))) void*)(dst), 16, 0, 0)

#define BAR() do { __builtin_amdgcn_sched_barrier(0); \
                   asm volatile("" ::: "memory"); \
                   __builtin_amdgcn_s_barrier(); \
                   asm volatile("" ::: "memory"); \
                   __builtin_amdgcn_sched_barrier(0); } while (0)

#define MFMA16 __builtin_amdgcn_mfma_f32_16x16x32_bf16

// ---------------- fp32 -> bf16 convert (vectorized x4) ----------------
__global__ __launch_bounds__(256)
void cvt_f32_bf16(const float* __restrict__ in, bf16* __restrict__ out, int n4)
{
    int i = blockIdx.x * 256 + threadIdx.x;
    if (i >= n4) return;
    float4 v = ((const float4*)in)[i];
    bf16x4 o = { (bf16)v.x, (bf16)v.y, (bf16)v.z, (bf16)v.w };
    ((bf16x4*)out)[i] = o;
}

// ---------------- 256x256-tile, BK=64, 8-wave, 4-phase bf16 MFMA GEMM ----------------
// A[m][k], B[n][k] (K-contiguous).  C = A * B^T, fp32 accum.
// MODE 0: fused QKV  (B = [Wq;Wk;Wv], 3072 rows; epilogue Q/K bf16 + Vt transposed, +bias)
// MODE 2: scores     (triangular tile decode, out fp32 * 1/32)
// MODE 3: PV         (causal K truncation, out fp32)
template<int MODE>
__global__ __launch_bounds__(512, 2)
void gemm256(const bf16* __restrict__ Abase, const bf16* __restrict__ Bbase,
             const float* __restrict__ bqp, const float* __restrict__ bkp,
             const float* __restrict__ bvp,
             void* __restrict__ o0, void* __restrict__ o1, void* __restrict__ o2)
{
    // 2 dbuf x {A,B} x {half0,half1} x [128][64] bf16 = 8 x 16 KiB = 128 KiB
    __shared__ __align__(16) char smem[131072];

    int m0, n0;
    const int z = blockIdx.z;
    const bf16 *A, *Bm;
    int lda, ldb, nt;
    if constexpr (MODE == 0) {
        m0 = blockIdx.x * 256; n0 = blockIdx.y * 256;
        A = Abase; Bm = Bbase; lda = DIM; ldb = DIM; nt = 16;
    } else if constexpr (MODE == 2) {
        // lower-triangle tile decode: u -> (mi, ni), ni <= mi, 8x8 tile grid
        int u = blockIdx.x, mi = 0;
        while ((mi + 1) * (mi + 2) / 2 <= u) ++mi;
        int ni = u - mi * (mi + 1) / 2;
        m0 = mi * 256; n0 = ni * 256;
        A  = Abase + (size_t)z * L_SEQ * DIM;
        Bm = Bbase + (size_t)z * L_SEQ * DIM;
        lda = DIM; ldb = DIM; nt = 16;
    } else {
        m0 = blockIdx.x * 256; n0 = blockIdx.y * 256;
        A  = Abase + (size_t)z * L_SEQ * L_SEQ;
        Bm = Bbase + (size_t)z * DIM * L_SEQ;
        lda = L_SEQ; ldb = L_SEQ; nt = (m0 >> 6) + 4;     // k <= m0+255 only (wts==0 beyond)
    }

    const int tid  = threadIdx.x;
    const int w    = tid >> 6, lane = tid & 63;
    const int wm   = w >> 2, wn = w & 3;                   // 2 (M) x 4 (N) waves
    const int l15  = lane & 15, lh = lane >> 4;

    // ---- staging geometry: per wave 2 issues of 1 KiB per half-tile ----
    // physical byte within half-tile: p = (w*2+c)*1024 + lane*16 (linear dest)
    // logical element offset: L = p ^ ((row-bits)<<4)   (swizzle involution)
    const int p0 = (w * 2 + 0) * 1024 + lane * 16;
    const int p1 = (w * 2 + 1) * 1024 + lane * 16;
    const int L0 = p0 ^ (((p0 >> 7) & 7) << 4);
    const int L1 = p1 ^ (((p1 >> 7) & 7) << 4);
    const int sr0 = L0 >> 7, sc0 = (L0 & 127) >> 1;        // row 0..127, col-elem 0..63
    const int sr1 = L1 >> 7, sc1 = (L1 & 127) >> 1;

    f32x4 acc[8][4];
#pragma unroll
    for (int i = 0; i < 8; ++i)
#pragma unroll
        for (int j = 0; j < 4; ++j) acc[i][j] = (f32x4){0.f, 0.f, 0.f, 0.f};

    int cur = 0;

    auto stage_half = [&](int buf, int op, int half, int kt) {
        const bf16* ob = (op == 0) ? A : Bm;
        const int  ld  = (op == 0) ? lda : ldb;
        const int  r0  = ((op == 0) ? m0 : n0) + half * 128;
        const int  k0  = kt << 6;
        char* ldsb = smem + ((((buf << 1) | op) << 1 | half) * 16384);
        GLDS(ob + (size_t)(r0 + sr0) * ld + (k0 + sc0), ldsb + (w * 2 + 0) * 1024);
        GLDS(ob + (size_t)(r0 + sr1) * ld + (k0 + sc1), ldsb + (w * 2 + 1) * 1024);
    };
    auto rdA = [&](int i, int kk) -> bf16x8 {              // i 0..7 within wave's 128-row span
        int lr = i * 16 + l15;
        int p  = lr * 128 + kk * 64 + (lh << 4);
        p ^= ((lr & 7) << 4);
        return *(const bf16x8*)(smem + ((((cur << 1) | 0) << 1 | wm) * 16384) + p);
    };
    auto rdB = [&](int j, int kk) -> bf16x8 {              // j 0..3 within wave's 64-col span
        int c = wn * 64 + j * 16 + l15;                    // 0..255
        int half = c >> 7, lr = c & 127;
        int p = lr * 128 + kk * 64 + (lh << 4);
        p ^= ((lr & 7) << 4);
        return *(const bf16x8*)(smem + ((((cur << 1) | 1) << 1 | half) * 16384) + p);
    };

    // ---- prologue: stage tile 0 into buf0, drain, barrier ----
    stage_half(0, 0, 0, 0); stage_half(0, 0, 1, 0);
    stage_half(0, 1, 0, 0); stage_half(0, 1, 1, 0);
    asm volatile("s_waitcnt vmcnt(0)" ::: "memory");
    __builtin_amdgcn_s_barrier();
    asm volatile("" ::: "memory");

    for (int t = 0; t < nt; ++t) {
        const bool pref = (t + 1 < nt);
        const int  nxt  = cur ^ 1;
        bf16x8 afr[4][2], b0r[2][2], b1r[2][2];

        // ---- P1: quadrant (rows 0-63, cols 0-31 of wave) ----
#pragma unroll
        for (int i = 0; i < 4; ++i) { afr[i][0] = rdA(i, 0); afr[i][1] = rdA(i, 1); }
#pragma unroll
        for (int j = 0; j < 2; ++j) { b0r[j][0] = rdB(j, 0); b0r[j][1] = rdB(j, 1); }
        if (pref) { stage_half(nxt, 0, 0, t + 1); stage_half(nxt, 1, 0, t + 1); }
        BAR();
        __builtin_amdgcn_s_setprio(1);
#pragma unroll
        for (int i = 0; i < 4; ++i)
#pragma unroll
            for (int j = 0; j < 2; ++j) {
                acc[i][j] = MFMA16(afr[i][0], b0r[j][0], acc[i][j], 0, 0, 0);
                acc[i][j] = MFMA16(afr[i][1], b0r[j][1], acc[i][j], 0, 0, 0);
            }
        __builtin_amdgcn_s_setprio(0);
        BAR();

        // ---- P2: (rows 0-63, cols 32-63) ----
#pragma unroll
        for (int j = 0; j < 2; ++j) { b1r[j][0] = rdB(j + 2, 0); b1r[j][1] = rdB(j + 2, 1); }
        if (pref) { stage_half(nxt, 1, 1, t + 1); stage_half(nxt, 0, 1, t + 1); }
        BAR();
        __builtin_amdgcn_s_setprio(1);
#pragma unroll
        for (int i = 0; i < 4; ++i)
#pragma unroll
            for (int j = 0; j < 2; ++j) {
                acc[i][j + 2] = MFMA16(afr[i][0], b1r[j][0], acc[i][j + 2], 0, 0, 0);
                acc[i][j + 2] = MFMA16(afr[i][1], b1r[j][1], acc[i][j + 2], 0, 0, 0);
            }
        __builtin_amdgcn_s_setprio(0);
        BAR();

        // ---- P3: (rows 64-127, cols 32-63) ----
#pragma unroll
        for (int i = 0; i < 4; ++i) { afr[i][0] = rdA(i + 4, 0); afr[i][1] = rdA(i + 4, 1); }
        BAR();
        __builtin_amdgcn_s_setprio(1);
#pragma unroll
        for (int i = 0; i < 4; ++i)
#pragma unroll
            for (int j = 0; j < 2; ++j) {
                acc[i + 4][j + 2] = MFMA16(afr[i][0], b1r[j][0], acc[i + 4][j + 2], 0, 0, 0);
                acc[i + 4][j + 2] = MFMA16(afr[i][1], b1r[j][1], acc[i + 4][j + 2], 0, 0, 0);
            }
        __builtin_amdgcn_s_setprio(0);
        BAR();

        // ---- P4: (rows 64-127, cols 0-31); tile-boundary residency wait ----
        __builtin_amdgcn_s_setprio(1);
#pragma unroll
        for (int i = 0; i < 4; ++i)
#pragma unroll
            for (int j = 0; j < 2; ++j) {
                acc[i + 4][j] = MFMA16(afr[i][0], b0r[j][0], acc[i + 4][j], 0, 0, 0);
                acc[i + 4][j] = MFMA16(afr[i][1], b0r[j][1], acc[i + 4][j], 0, 0, 0);
            }
        __builtin_amdgcn_s_setprio(0);
        asm volatile("s_waitcnt vmcnt(0)" ::: "memory");   // nothing newer in flight: next tile resident
        BAR();
        cur = nxt;
    }

    // ---- epilogue: C/D frag layout col = lane&15, row = (lane>>4)*4 + r ----
    const int lr4 = lh << 2;

    if constexpr (MODE == 0) {
        const int sel = n0 >> 10;                 // 0:Q 1:K 2:V (uniform per block; 1024%256==0)
        const int nb  = n0 & 1023;
        const float* bias = (sel == 0) ? bqp : ((sel == 1) ? bkp : bvp);
        if (sel < 2) {
            bf16* out = (sel == 0) ? (bf16*)o0 : (bf16*)o1;
#pragma unroll
            for (int i = 0; i < 8; ++i) {
                int row0 = m0 + wm * 128 + i * 16 + lr4;
#pragma unroll
                for (int j = 0; j < 4; ++j) {
                    int col = nb + wn * 64 + j * 16 + l15;
                    float bb = bias[col];
#pragma unroll
                    for (int r = 0; r < 4; ++r)
                        out[(size_t)(row0 + r) * DIM + col] = (bf16)(acc[i][j][r] + bb);
                }
            }
        } else {
            bf16* Vt = (bf16*)o2;
#pragma unroll
            for (int i = 0; i < 8; ++i) {
                int row0 = m0 + wm * 128 + i * 16 + lr4;
                int b = row0 >> 11, l = row0 & 2047;
#pragma unroll
                for (int j = 0; j < 4; ++j) {
                    int col = nb + wn * 64 + j * 16 + l15;
                    float bb = bias[col];
                    bf16x4 v = { (bf16)(acc[i][j][0] + bb), (bf16)(acc[i][j][1] + bb),
                                 (bf16)(acc[i][j][2] + bb), (bf16)(acc[i][j][3] + bb) };
                    *(bf16x4*)(Vt + ((size_t)b * DIM + col) * L_SEQ + l) = v;
                }
            }
        }
    } else if constexpr (MODE == 2) {
        float* sc = (float*)o0 + (size_t)z * L_SEQ * L_SEQ;
#pragma unroll
        for (int i = 0; i < 8; ++i) {
            int row0 = m0 + wm * 128 + i * 16 + lr4;
#pragma unroll
            for (int j = 0; j < 4; ++j) {
                int col = n0 + wn * 64 + j * 16 + l15;
#pragma unroll
                for (int r = 0; r < 4; ++r)
                    sc[(size_t)(row0 + r) * L_SEQ + col] = acc[i][j][r] * 0.03125f;
            }
        }
    } else {
        float* o = (float*)o0 + (size_t)z * L_SEQ * DIM;
#pragma unroll
        for (int i = 0; i < 8; ++i) {
            int row0 = m0 + wm * 128 + i * 16 + lr4;
#pragma unroll
            for (int j = 0; j < 4; ++j) {
                int col = n0 + wn * 64 + j * 16 + l15;
#pragma unroll
                for (int r = 0; r < 4; ++r)
                    o[(size_t)(row0 + r) * DIM + col] = acc[i][j][r];
            }
        }
    }
}

// ---------------- causal row softmax: wts fp32 (in-place) + bf16 copy ----------------
__global__ __launch_bounds__(256)
void softmax_rows(float* __restrict__ wts, bf16* __restrict__ Pb)
{
    const int row = blockIdx.x;                 // 0..8191
    const int q = row & 2047;
    float* s = wts + (size_t)row * L_SEQ;
    bf16*  p = Pb  + (size_t)row * L_SEQ;
    const int t = threadIdx.x;
    const int lane = t & 63, w = t >> 6;
    const int k0 = t * 8;

    float v[8];
    if (k0 + 7 <= q) {
        float4 a = *(const float4*)(s + k0);
        float4 b = *(const float4*)(s + k0 + 4);
        v[0]=a.x; v[1]=a.y; v[2]=a.z; v[3]=a.w;
        v[4]=b.x; v[5]=b.y; v[6]=b.z; v[7]=b.w;
    } else {
#pragma unroll
        for (int c = 0; c < 8; ++c) {
            int k = k0 + c;
            v[c] = (k <= q) ? s[k] : -3.0e38f;
        }
    }

    float mx = v[0];
#pragma unroll
    for (int c = 1; c < 8; ++c) mx = fmaxf(mx, v[c]);
#pragma unroll
    for (int off = 32; off; off >>= 1) mx = fmaxf(mx, __shfl_xor(mx, off));
    __shared__ float redm[4];
    if (lane == 0) redm[w] = mx;
    __syncthreads();
    mx = fmaxf(fmaxf(redm[0], redm[1]), fmaxf(redm[2], redm[3]));

    float sm = 0.f;
#pragma unroll
    for (int c = 0; c < 8; ++c) {
        float e = __expf(v[c] - mx);             // masked -> exp(-inf) == 0 exactly
        v[c] = e;
        sm += e;
    }
#pragma unroll
    for (int off = 32; off; off >>= 1) sm += __shfl_xor(sm, off);
    __shared__ float reds[4];
    if (lane == 0) reds[w] = sm;
    __syncthreads();
    sm = reds[0] + reds[1] + reds[2] + reds[3];
    const float inv = 1.f / sm;

    float o[8];
#pragma unroll
    for (int c = 0; c < 8; ++c) o[c] = v[c] * inv;
    float4 s0 = { o[0], o[1], o[2], o[3] };
    float4 s1 = { o[4], o[5], o[6], o[7] };
    *(float4*)(s + k0)     = s0;
    *(float4*)(s + k0 + 4) = s1;
    bf16x8 pb = { (bf16)o[0], (bf16)o[1], (bf16)o[2], (bf16)o[3],
                  (bf16)o[4], (bf16)o[5], (bf16)o[6], (bf16)o[7] };
    *(bf16x8*)(p + k0) = pb;
}

extern "C" void kernel_launch(void* const* d_in, const int* in_sizes, int n_in,
                              void* d_out, int out_size, void* d_ws, size_t ws_size,
                              hipStream_t stream)
{
    const float* x  = (const float*)d_in[0];
    const float* Wq = (const float*)d_in[1];
    const float* bq = (const float*)d_in[2];
    const float* Wk = (const float*)d_in[3];
    const float* bk = (const float*)d_in[4];
    const float* Wv = (const float*)d_in[5];
    const float* bv = (const float*)d_in[6];

    float* out = (float*)d_out;                               // [4][2048][1024]
    float* wts = out + (size_t)BATCH * L_SEQ * DIM;           // [4][2048][2048]

    char* ws = (char*)d_ws;
    bf16* Xb   = (bf16*)(ws + 0);                  // 16 MiB  [8192][1024]
    bf16* Wcat = (bf16*)(ws + (16u  << 20));       //  6 MiB  [3072][1024]  (Wq;Wk;Wv)
    bf16* Qb   = (bf16*)(ws + (22u  << 20));       // 16 MiB  [b][l][e]
    bf16* Kb   = (bf16*)(ws + (38u  << 20));       // 16 MiB  [b][l][e]
    bf16* Vt   = (bf16*)(ws + (54u  << 20));       // 16 MiB  [b][e][l]
    bf16* Pb   = (bf16*)(ws + (70u  << 20));       // 32 MiB  [b][q][k]

    cvt_f32_bf16<<<dim3(8192), dim3(256), 0, stream>>>(x,  Xb, 8388608 / 4);
    cvt_f32_bf16<<<dim3(1024), dim3(256), 0, stream>>>(Wq, Wcat,           1048576 / 4);
    cvt_f32_bf16<<<dim3(1024), dim3(256), 0, stream>>>(Wk, Wcat + 1048576, 1048576 / 4);
    cvt_f32_bf16<<<dim3(1024), dim3(256), 0, stream>>>(Wv, Wcat + 2097152, 1048576 / 4);

    gemm256<0><<<dim3(32, 12, 1), dim3(512), 0, stream>>>(Xb, Wcat, bq, bk, bv, Qb, Kb, Vt);
    gemm256<2><<<dim3(36, 1, 4),  dim3(512), 0, stream>>>(Qb, Kb, nullptr, nullptr, nullptr, wts, nullptr, nullptr);
    softmax_rows<<<dim3(8192), dim3(256), 0, stream>>>(wts, Pb);
    gemm256<3><<<dim3(8, 4, 4),   dim3(512), 0, stream>>>(Pb, Vt, nullptr, nullptr, nullptr, out, nullptr, nullptr);
}